// Round 4
// baseline (292.183 us; speedup 1.0000x reference)
//
#include <hip/hip_runtime.h>

#define TLEN 100
#define ECN  100
#define CA1N 100
#define CA3N 100
#define BSZ  4096
#define ACTN 2
#define BT   8      // batch rows per block (M-tile rows 8..15 are dead padding)

typedef short bf16x8 __attribute__((ext_vector_type(8)));
typedef float f32x4  __attribute__((ext_vector_type(4)));

__device__ __forceinline__ unsigned short f2bf(float f){ // round-half-up bf16
  union { float f; unsigned int u; } c; c.f = f;
  return (unsigned short)((c.u + 0x8000u) >> 16);
}
__device__ __forceinline__ float fsigm(float x){ // 1/(1+exp(-x)), fast rcp
  float e = __expf(-x);
  return __builtin_amdgcn_rcpf(1.0f + e);
}
// LDS-only barrier: syncs waves + drains LDS ops, but does NOT drain vmcnt —
// global stores (out_his, write-only, never read back) stay in flight.
__device__ __forceinline__ void lds_barrier(){
  asm volatile("s_waitcnt lgkmcnt(0)\n\ts_barrier" ::: "memory");
}

// ---- kernel 0: drive[t][j] = sum_k exp(-((t-c_k)/5)^2/2) * Wca3ca1[k][j] ----
__global__ void drive_kernel(const float* __restrict__ Wca3ca1, float* __restrict__ drive){
  __shared__ float ca3row[CA3N];
  const int t = blockIdx.x, tid = threadIdx.x;
  if (tid < CA3N){
    float c = (float)tid * (100.0f / 99.0f);   // linspace(0,100,100)
    float d = ((float)t - c) * 0.2f;           // /SIGMA=5
    ca3row[tid] = __expf(-0.5f * d * d);
  }
  __syncthreads();
  if (tid < CA1N){
    float acc = 0.f;
    for (int k = 0; k < CA3N; ++k) acc = fmaf(ca3row[k], Wca3ca1[k*CA1N + tid], acc);
    drive[t*CA1N + tid] = acc;
  }
}

// frag-linear bf16 A-shadow: element (m,k) at  (k>>5)*512 + (m + 16*((k>>3)&3))*8 + (k&7)
// so a wave's ds_read_b128 at (ks*1024 + lane*16) bytes is lane-contiguous.

__global__ __launch_bounds__(512, 4)
void rnn_kernel(const int*   __restrict__ cue_train,
                const float* __restrict__ ec3_last,
                const float* __restrict__ ec5_last,
                const float* __restrict__ cueL,
                const float* __restrict__ cueR,
                const float* __restrict__ Wec3ca1,
                const float* __restrict__ Wca1ec5,
                const float* __restrict__ Wca1act,
                const float* __restrict__ ca1bias,
                const float* __restrict__ drive,
                float*       __restrict__ out)
{
  __shared__ __align__(16) unsigned short ec3b[2048];   // frag-linear bf16 ec3 (4 KB)
  __shared__ __align__(16) unsigned short ca1b[2048];   // frag-linear bf16 ca1 (4 KB)
  __shared__ __align__(16) float driveS[TLEN * CA1N];   // 40 KB, kills in-loop global loads
  __shared__ __align__(16) float ca1f[BT * 132];        // final ca1 (epilogue)
  __shared__ __align__(4)  signed char cueT[TLEN * BT]; // cue transposed [t][r]

  const int tid = threadIdx.x;
  const int b0  = blockIdx.x * BT;

  float* out_act = out;
  float* out_his = out + (size_t)BSZ * ACTN;
  float* out_e3  = out_his + (size_t)TLEN * BSZ * CA1N;
  float* out_e5  = out_e3 + (size_t)BSZ * ECN;
  float* out_c1  = out_e5 + (size_t)BSZ * ECN;

  // --- zero frag shadows; stage drive + cue into LDS ---
  for (int idx = tid; idx < 2048; idx += 512){ ec3b[idx] = 0; ca1b[idx] = 0; }
  {
    const float4* src = (const float4*)drive;
    float4*       dst = (float4*)driveS;
    for (int idx = tid; idx < TLEN * CA1N / 4; idx += 512) dst[idx] = src[idx];
  }
  for (int idx = tid; idx < BT * TLEN; idx += 512){
    int t = idx >> 3, r = idx & 7;
    cueT[t * BT + r] = (signed char)cue_train[(size_t)(b0 + r) * TLEN + t];
  }

  const int lane  = tid & 63;
  const int wv    = tid >> 6;          // wave id = N-tile id (0..7)
  const int col16 = lane & 15;
  const int q     = lane >> 4;         // quad
  const int col   = wv * 16 + col16;   // output column (CA1 ph1 / EC ph2)
  const bool okc  = (col < CA1N);
  const bool rowok = (q < 2);          // rows q*4+i < 8 are real
  const bool wactive = (wv < 7);       // wave 7: cols 112..127 all dead
  const int colc  = okc ? col : 0;

  // per-lane frag-write base (shorts), k=col, m=q*4+i
  const int abase = (col >> 5) * 512 + ((col >> 3) & 3) * 128 + (col & 7) + q * 32;

  // --- B-fragments in registers (bf16 weights); zero-padded k>=100 / col>=100 ---
  bf16x8 b1[4], b2[4];
  #pragma unroll
  for (int ks = 0; ks < 4; ++ks){
    #pragma unroll
    for (int jj = 0; jj < 8; ++jj){
      int k = ks * 32 + q * 8 + jj;
      float w1 = 0.f, w2 = 0.f;
      if (k < ECN && okc){
        w1 = Wec3ca1[k * CA1N + col];
        w2 = Wca1ec5[k * ECN  + col];
      }
      b1[ks][jj] = (short)f2bf(w1);
      b2[ks][jj] = (short)f2bf(w2);
    }
  }
  const float bias_c = okc ? ca1bias[col] : 0.f;
  const float cL = okc ? cueL[col] : 0.f;
  const float cR = okc ? cueR[col] : 0.f;

  __syncthreads();  // zeros + staging complete

  // --- fp32 state in registers (lane owns (r=q*4+i, col)) ---
  float ec3v[4], ec5v[4], c1[4] = {0.f,0.f,0.f,0.f};
  #pragma unroll
  for (int i = 0; i < 4; ++i){
    int r = q * 4 + i;
    float v3 = (okc && rowok) ? ec3_last[(size_t)(b0 + r) * ECN + col] : 0.f;
    float v5 = (okc && rowok) ? ec5_last[(size_t)(b0 + r) * ECN + col] : 0.f;
    ec3v[i] = v3; ec5v[i] = v5;
    if (okc) ec3b[abase + i * 8] = f2bf(v3);
  }
  __syncthreads();  // ec3b ready

  float* hp = out_his + (size_t)(b0 + (rowok ? q * 4 : 0)) * CA1N + colc;
  const int cuoff = rowok ? q * 4 : 0;

  const bf16x8* fe3 = (const bf16x8*)ec3b;   // chunk ks at index ks*64+lane
  const bf16x8* fc1 = (const bf16x8*)ca1b;

  for (int t = 0; t < TLEN; ++t){
    float dv  = driveS[t * CA1N + colc];                  // LDS, no vmcnt
    int   cu4 = *(const int*)(cueT + t * BT + cuoff);     // 4 cue bytes

    // ---- phase 1: z = ec3 @ W1 ; ca1 = relu(dv*(1+sig(z)) - bias) ----
    if (wactive){
      f32x4 aA = {0.f,0.f,0.f,0.f}, aB = {0.f,0.f,0.f,0.f};
      bf16x8 a0 = fe3[  0 + lane];
      bf16x8 a1 = fe3[ 64 + lane];
      bf16x8 a2 = fe3[128 + lane];
      bf16x8 a3 = fe3[192 + lane];
      aA = __builtin_amdgcn_mfma_f32_16x16x32_bf16(a0, b1[0], aA, 0, 0, 0);
      aB = __builtin_amdgcn_mfma_f32_16x16x32_bf16(a1, b1[1], aB, 0, 0, 0);
      aA = __builtin_amdgcn_mfma_f32_16x16x32_bf16(a2, b1[2], aA, 0, 0, 0);
      aB = __builtin_amdgcn_mfma_f32_16x16x32_bf16(a3, b1[3], aB, 0, 0, 0);
      f32x4 z = aA + aB;
      float dmb = dv - bias_c;
      #pragma unroll
      for (int i = 0; i < 4; ++i){
        float v = fmaxf(fmaf(dv, fsigm(z[i]), dmb), 0.f);
        c1[i] = v;
        if (okc) ca1b[abase + i * 8] = f2bf(v);
      }
    }
    lds_barrier();

    // out_his stores: fire-and-forget, drain under later compute (no vmcnt at barriers)
    if (okc && rowok){
      hp[0 * CA1N] = c1[0];
      hp[1 * CA1N] = c1[1];
      hp[2 * CA1N] = c1[2];
      hp[3 * CA1N] = c1[3];
    }
    hp += (size_t)BSZ * CA1N;

    // ---- phase 2: z2 = ca1 @ W2 ; ec5/ec3 register update ----
    if (wactive){
      f32x4 aA = {0.f,0.f,0.f,0.f}, aB = {0.f,0.f,0.f,0.f};
      bf16x8 a0 = fc1[  0 + lane];
      bf16x8 a1 = fc1[ 64 + lane];
      bf16x8 a2 = fc1[128 + lane];
      bf16x8 a3 = fc1[192 + lane];
      aA = __builtin_amdgcn_mfma_f32_16x16x32_bf16(a0, b2[0], aA, 0, 0, 0);
      aB = __builtin_amdgcn_mfma_f32_16x16x32_bf16(a1, b2[1], aB, 0, 0, 0);
      aA = __builtin_amdgcn_mfma_f32_16x16x32_bf16(a2, b2[2], aA, 0, 0, 0);
      aB = __builtin_amdgcn_mfma_f32_16x16x32_bf16(a3, b2[3], aB, 0, 0, 0);
      f32x4 z2 = aA + aB;
      #pragma unroll
      for (int i = 0; i < 4; ++i){
        float x  = ec5v[i] + z2[i];
        float e5 = fmaf(0.3f, fsigm(fmaf(4.0f, x, -1.2f)), 0.69f);
        ec5v[i] = e5;
        int cu = (cu4 >> (8 * i)) & 0xff;                 // -1 -> 0xff
        float sns = (cu == 1) ? cL : ((cu == 0xff) ? cR : 0.0f);
        float e3 = fmaf(e5, ec3v[i], sns);
        ec3v[i] = e3;
        if (okc) ec3b[abase + i * 8] = f2bf(e3);
      }
    }
    lds_barrier();
  }

  // ---- epilogue: dump final states from registers ----
  if (okc && rowok){
    #pragma unroll
    for (int i = 0; i < 4; ++i){
      int r = q * 4 + i;
      size_t g = (size_t)(b0 + r) * ECN + col;
      out_e3[g] = ec3v[i];
      out_e5[g] = ec5v[i];
      out_c1[g] = c1[i];
      ca1f[r * 132 + col] = c1[i];
    }
  }
  __syncthreads();

  // actCell = ca1_final @ Wca1act
  if (tid < BT * ACTN){
    int r = tid >> 1, a = tid & 1;
    float acc = 0.f;
    for (int jj = 0; jj < CA1N; ++jj)
      acc = fmaf(ca1f[r * 132 + jj], Wca1act[jj * ACTN + a], acc);
    out_act[(size_t)(b0 + r) * ACTN + a] = acc;
  }
}

extern "C" void kernel_launch(void* const* d_in, const int* in_sizes, int n_in,
                              void* d_out, int out_size, void* d_ws, size_t ws_size,
                              hipStream_t stream) {
  (void)in_sizes; (void)n_in; (void)out_size; (void)ws_size;
  const int*   cue_train = (const int*)  d_in[1];
  const float* ec3_last  = (const float*)d_in[2];
  const float* ec5_last  = (const float*)d_in[3];
  const float* cueL      = (const float*)d_in[5];
  const float* cueR      = (const float*)d_in[6];
  const float* Wec3ca1   = (const float*)d_in[7];
  const float* Wca3ca1   = (const float*)d_in[8];
  const float* Wca1ec5   = (const float*)d_in[9];
  const float* Wca1act   = (const float*)d_in[10];
  const float* ca1bias   = (const float*)d_in[11];
  float* out   = (float*)d_out;
  float* drive = (float*)d_ws;   // 100*100 fp32 = 40 KB scratch

  drive_kernel<<<TLEN, 128, 0, stream>>>(Wca3ca1, drive);
  rnn_kernel<<<BSZ / BT, 512, 0, stream>>>(cue_train, ec3_last, ec5_last,
                                           cueL, cueR, Wec3ca1, Wca1ec5,
                                           Wca1act, ca1bias, drive, out);
}